// Round 6
// baseline (189.161 us; speedup 1.0000x reference)
//
#include <hip/hip_runtime.h>
#include <math.h>

#define N_PTS 50000
#define CCH   64
#define KP    15
#define NH    32
#define SIGMA 0.7f
#define BN_EPS 1e-5f
#define LEAKY 0.1f
#define QB    16
#define CWS   17           // cwT row stride in bf16: odd stride -> 2-way banks (free)
#define STATS_BLOCKS 1024

typedef short bf16x8 __attribute__((ext_vector_type(8)));
typedef float floatx4 __attribute__((ext_vector_type(4)));

__device__ __forceinline__ unsigned short f2b(float f) {
    union { float f; unsigned u; } v; v.f = f;
    return (unsigned short)((v.u + 0x7FFFu + ((v.u >> 16) & 1u)) >> 16);  // RNE
}
__device__ __forceinline__ float b2f(unsigned short b) {
    union { unsigned u; float f; } v; v.u = ((unsigned)b) << 16;
    return v.f;
}

// ---------- K1: blocks [0,STATS): h = sf@W1 -> hst (bf16) + BN sum/sumsq.
//             blocks [STATS, STATS+30): repack W2 into bf16 B-fragment order. ----------
__global__ __launch_bounds__(256) void k_prep(const float* __restrict__ sf,
                                              const float* __restrict__ W1,
                                              const float* __restrict__ W2,
                                              float* __restrict__ bn,
                                              unsigned short* __restrict__ hst,
                                              unsigned short* __restrict__ w2b) {
    int t = threadIdx.x;
    if (blockIdx.x >= STATS_BLOCKS) {
        // w2b[((tile*2+kstep)*64+lane)*8+j] = bf16(W2[k][n]),
        //   k = kstep*32 + (lane>>4)*8 + j, n = tile*16 + (lane&15)
        int g = (blockIdx.x - STATS_BLOCKS) * 256 + t;   // 7680 exactly
        int lane = g & 63, s = (g >> 6) & 1, tt = g >> 7;
        int col = lane & 15, quad = lane >> 4;
        int base = (s * 32 + quad * 8) * 960 + tt * 16 + col;
        ushort4 lo, hi;
        lo.x = f2b(W2[base + 0 * 960]); lo.y = f2b(W2[base + 1 * 960]);
        lo.z = f2b(W2[base + 2 * 960]); lo.w = f2b(W2[base + 3 * 960]);
        hi.x = f2b(W2[base + 4 * 960]); hi.y = f2b(W2[base + 5 * 960]);
        hi.z = f2b(W2[base + 6 * 960]); hi.w = f2b(W2[base + 7 * 960]);
        *(ushort4*)(w2b + g * 8)     = lo;
        *(ushort4*)(w2b + g * 8 + 4) = hi;
        return;
    }
    int c = t & 63, ml = t >> 6;
    float w1c[64];
    #pragma unroll
    for (int i = 0; i < 64; ++i) w1c[i] = W1[i * 64 + c];
    __shared__ float rows[4][64];
    float acc_s = 0.f, acc_q = 0.f;
    for (int m0 = blockIdx.x * 4; m0 < N_PTS; m0 += STATS_BLOCKS * 4) {
        __syncthreads();
        ((float*)rows)[t] = sf[m0 * 64 + t];
        __syncthreads();
        float h = 0.f;
        #pragma unroll
        for (int i4 = 0; i4 < 16; ++i4) {
            float4 r = *(const float4*)&rows[ml][i4 * 4];
            h += r.x * w1c[i4 * 4] + r.y * w1c[i4 * 4 + 1]
               + r.z * w1c[i4 * 4 + 2] + r.w * w1c[i4 * 4 + 3];
        }
        acc_s += h;
        acc_q += h * h;
        hst[(m0 + ml) * 64 + c] = f2b(h);      // 128B/wave coalesced
    }
    __shared__ float red[2][256];
    red[0][t] = acc_s; red[1][t] = acc_q;
    __syncthreads();
    if (t < 64) {
        float s = red[0][t] + red[0][64 + t] + red[0][128 + t] + red[0][192 + t];
        float q = red[1][t] + red[1][64 + t] + red[1][128 + t] + red[1][192 + t];
        atomicAdd(&bn[t], s);
        atomicAdd(&bn[64 + t], q);
    }
}

// ---------- K2: fused main. 256 threads / 4 waves (round-3 shape: VGPR~60-110,
// NOT 512/1024 threads: rounds 4+5 showed the compiler then trims unified VGPR
// budget to 64 -> 32 arch VGPRs -> no memory-level parallelism). ----------
__global__ __launch_bounds__(256, 4) void k_main(
    const float* __restrict__ q_pts, const float* __restrict__ s_pts,
    const float* __restrict__ s_feats, const int* __restrict__ nb,
    const float* __restrict__ kpts, const float* __restrict__ gamma,
    const float* __restrict__ beta, const float* __restrict__ bn,
    const float* __restrict__ b2, const unsigned short* __restrict__ w2b,
    const unsigned short* __restrict__ hst, float* __restrict__ out) {

    __shared__ __align__(16) unsigned short cwT[960 * CWS];  // 32.64 KB: cw[n][q] bf16
    __shared__ float abS[128];                               // BN fold a[64], b[64]
    __shared__ float kp[48];
    __shared__ int      nCnt[QB];
    __shared__ unsigned nPack[QB][NH];    // idx(0:15) | k(16:19) | infl_q12(20:31)

    int t = threadIdx.x;
    int lane = t & 63, wv = t >> 6;       // wv in [0,4)
    int m0 = blockIdx.x * QB;

    // ---- init LDS ----
    if (t < 64) {   // inline BN finalize
        float mu  = bn[t] * (1.0f / N_PTS);
        float var = bn[64 + t] * (1.0f / N_PTS) - mu * mu;
        float a   = gamma[t] * rsqrtf(var + BN_EPS);
        abS[t]      = a;
        abS[64 + t] = beta[t] - mu * a;
    } else if (t < 64 + 45) {
        kp[t - 64] = kpts[t - 64];
    } else if (t >= 112 && t < 112 + QB) {
        nCnt[t - 112] = 0;
    }
    ((unsigned*)nPack)[t]       = 0u;     // zero-pad for branch-free phase B
    ((unsigned*)nPack)[t + 256] = 0u;
    __syncthreads();

    // ---- issue phase-1 loads early (2 tasks/thread) ----
    int qA = t >> 5,        hA = t & 31;        int mA = m0 + qA;
    int qBq = (t + 256) >> 5, hB = t & 31;      int mB = m0 + qBq;
    int idxA = nb[mA * NH + hA];
    int idxB = nb[mB * NH + hB];
    float qAx = q_pts[mA * 3 + 0], qAy = q_pts[mA * 3 + 1], qAz = q_pts[mA * 3 + 2];
    float qBx = q_pts[mB * 3 + 0], qBy = q_pts[mB * 3 + 1], qBz = q_pts[mB * 3 + 2];

    int row = lane & 15, half = lane >> 4;
    const unsigned short* hrow = hst + (m0 + row) * 64 + half * 8;
    bf16x8 r0 = *(const bf16x8*)(hrow);        // c = half*8 + j
    bf16x8 r1 = *(const bf16x8*)(hrow + 32);   // c = 32 + half*8 + j

    // ---- A-fragment build: fold BN + leaky (overlaps nb/q_pts latency) ----
    bf16x8 a0, a1;
    #pragma unroll
    for (int j = 0; j < 8; ++j) {
        int c0 = half * 8 + j;
        float g0 = abS[c0] * b2f((unsigned short)r0[j]) + abS[64 + c0];
        g0 = g0 > 0.f ? g0 : LEAKY * g0;
        a0[j] = (short)f2b(g0);
        int c1 = 32 + c0;
        float g1 = abS[c1] * b2f((unsigned short)r1[j]) + abS[64 + c1];
        g1 = g1 > 0.f ? g1 : LEAKY * g1;
        a1[j] = (short)f2b(g1);
    }

    // ---- issue s_pts gathers (idx has landed) ----
    float sAx = s_pts[idxA * 3 + 0], sAy = s_pts[idxA * 3 + 1], sAz = s_pts[idxA * 3 + 2];
    float sBx = s_pts[idxB * 3 + 0], sBy = s_pts[idxB * 3 + 1], sBz = s_pts[idxB * 3 + 2];

    // ---- phase A: cw = G @ W2 via MFMA; wave owns 15 contiguous n-tiles ----
    {
        int col = lane & 15, quad = lane >> 4;
        for (int ti = 0; ti < 15; ++ti) {
            int tt = wv * 15 + ti;
            bf16x8 bf0 = *(const bf16x8*)(w2b + ((tt * 2 + 0) * 64 + lane) * 8);
            bf16x8 bf1 = *(const bf16x8*)(w2b + ((tt * 2 + 1) * 64 + lane) * 8);
            floatx4 acc = {0.f, 0.f, 0.f, 0.f};
            acc = __builtin_amdgcn_mfma_f32_16x16x32_bf16(a0, bf0, acc, 0, 0, 0);
            acc = __builtin_amdgcn_mfma_f32_16x16x32_bf16(a1, bf1, acc, 0, 0, 0);
            int n = tt * 16 + col;
            float bb = b2[n];
            unsigned short* dst = &cwT[n * CWS + quad * 4];   // D: row(q)=quad*4+reg
            ushort2 w01, w23;
            w01.x = f2b(acc[0] + bb); w01.y = f2b(acc[1] + bb);
            w23.x = f2b(acc[2] + bb); w23.y = f2b(acc[3] + bb);
            *(ushort2*)(dst)     = w01;
            *(ushort2*)(dst + 2) = w23;
        }
    }

    // ---- finish phase 1: 1-NN + influence for both tasks, packed append ----
    {
        float px = sAx - qAx, py = sAy - qAy, pz = sAz - qAz;
        float best = 1e30f; int bi = 0;
        #pragma unroll
        for (int k = 0; k < KP; ++k) {
            float dx = px - kp[k * 3], dy = py - kp[k * 3 + 1], dz = pz - kp[k * 3 + 2];
            float d = dx * dx + dy * dy + dz * dz;
            if (d < best) { best = d; bi = k; }
        }
        float infl = 1.f - sqrtf(best) * (1.0f / SIGMA);
        if (infl > 0.f) {
            int iq = (int)(infl * 4095.f + 0.5f);
            int pos = atomicAdd(&nCnt[qA], 1);
            nPack[qA][pos] = (unsigned)idxA | ((unsigned)bi << 16) | ((unsigned)iq << 20);
        }
        px = sBx - qBx; py = sBy - qBy; pz = sBz - qBz;
        best = 1e30f; bi = 0;
        #pragma unroll
        for (int k = 0; k < KP; ++k) {
            float dx = px - kp[k * 3], dy = py - kp[k * 3 + 1], dz = pz - kp[k * 3 + 2];
            float d = dx * dx + dy * dy + dz * dz;
            if (d < best) { best = d; bi = k; }
        }
        infl = 1.f - sqrtf(best) * (1.0f / SIGMA);
        if (infl > 0.f) {
            int iq = (int)(infl * 4095.f + 0.5f);
            int pos = atomicAdd(&nCnt[qBq], 1);
            nPack[qBq][pos] = (unsigned)idxB | ((unsigned)bi << 16) | ((unsigned)iq << 20);
        }
    }
    __syncthreads();

    // ---- phase B: wave owns 4 queries, ALL interleaved 2-wide -> 8 gathers
    //      + 8 LDS reads in flight, 4 independent FMA chains ----
    {
        int q0 = wv * 4, q1 = q0 + 1, q2 = q0 + 2, q3 = q0 + 3;
        int c = lane;
        int n01 = nCnt[q0] > nCnt[q1] ? nCnt[q0] : nCnt[q1];
        int n23 = nCnt[q2] > nCnt[q3] ? nCnt[q2] : nCnt[q3];
        int na  = n01 > n23 ? n01 : n23;
        float acc0 = 0.f, acc1 = 0.f, acc2 = 0.f, acc3 = 0.f;
        for (int jj = 0; jj < na; jj += 2) {
            uint2 p0 = *(const uint2*)&nPack[q0][jj];   // zero-padded: safe past count
            uint2 p1 = *(const uint2*)&nPack[q1][jj];
            uint2 p2 = *(const uint2*)&nPack[q2][jj];
            uint2 p3 = *(const uint2*)&nPack[q3][jj];
            // 8 independent global gathers
            float f00 = s_feats[(p0.x & 0xFFFFu) * 64 + c];
            float f01 = s_feats[(p0.y & 0xFFFFu) * 64 + c];
            float f10 = s_feats[(p1.x & 0xFFFFu) * 64 + c];
            float f11 = s_feats[(p1.y & 0xFFFFu) * 64 + c];
            float f20 = s_feats[(p2.x & 0xFFFFu) * 64 + c];
            float f21 = s_feats[(p2.y & 0xFFFFu) * 64 + c];
            float f30 = s_feats[(p3.x & 0xFFFFu) * 64 + c];
            float f31 = s_feats[(p3.y & 0xFFFFu) * 64 + c];
            // 8 LDS reads
            float w00 = b2f(cwT[(((p0.x >> 16) & 15u) * 64 + c) * CWS + q0]);
            float w01 = b2f(cwT[(((p0.y >> 16) & 15u) * 64 + c) * CWS + q0]);
            float w10 = b2f(cwT[(((p1.x >> 16) & 15u) * 64 + c) * CWS + q1]);
            float w11 = b2f(cwT[(((p1.y >> 16) & 15u) * 64 + c) * CWS + q1]);
            float w20 = b2f(cwT[(((p2.x >> 16) & 15u) * 64 + c) * CWS + q2]);
            float w21 = b2f(cwT[(((p2.y >> 16) & 15u) * 64 + c) * CWS + q2]);
            float w30 = b2f(cwT[(((p3.x >> 16) & 15u) * 64 + c) * CWS + q3]);
            float w31 = b2f(cwT[(((p3.y >> 16) & 15u) * 64 + c) * CWS + q3]);
            float i00 = (float)(p0.x >> 20), i01 = (float)(p0.y >> 20);
            float i10 = (float)(p1.x >> 20), i11 = (float)(p1.y >> 20);
            float i20 = (float)(p2.x >> 20), i21 = (float)(p2.y >> 20);
            float i30 = (float)(p3.x >> 20), i31 = (float)(p3.y >> 20);
            acc0 += i00 * f00 * w00 + i01 * f01 * w01;
            acc1 += i10 * f10 * w10 + i11 * f11 * w11;
            acc2 += i20 * f20 * w20 + i21 * f21 * w21;
            acc3 += i30 * f30 * w30 + i31 * f31 * w31;
        }
        const float qs = 1.f / 4095.f;
        out[(m0 + q0) * 64 + c] = acc0 * qs;
        out[(m0 + q1) * 64 + c] = acc1 * qs;
        out[(m0 + q2) * 64 + c] = acc2 * qs;
        out[(m0 + q3) * 64 + c] = acc3 * qs;
    }
}

extern "C" void kernel_launch(void* const* d_in, const int* in_sizes, int n_in,
                              void* d_out, int out_size, void* d_ws, size_t ws_size,
                              hipStream_t stream) {
    const float* q_pts   = (const float*)d_in[0];
    const float* s_pts   = (const float*)d_in[1];
    const float* s_feats = (const float*)d_in[2];
    const int*   nb      = (const int*)d_in[3];
    const float* kpts    = (const float*)d_in[4];
    const float* W1      = (const float*)d_in[5];
    const float* gamma   = (const float*)d_in[6];
    const float* beta    = (const float*)d_in[7];
    const float* W2      = (const float*)d_in[8];
    const float* b2      = (const float*)d_in[9];
    float* out = (float*)d_out;

    float* ws = (float*)d_ws;
    float* bn = ws;                                        // 128 fp32
    unsigned short* w2b = (unsigned short*)(ws + 128);     // 61440 bf16 (122880 B)
    unsigned short* hst = w2b + 61440;                     // 50000*64 bf16 (6.4 MB)

    hipMemsetAsync(bn, 0, 128 * sizeof(float), stream);
    k_prep<<<STATS_BLOCKS + 30, 256, 0, stream>>>(s_feats, W1, W2, bn, hst, w2b);
    k_main<<<N_PTS / QB, 256, 0, stream>>>(q_pts, s_pts, s_feats, nb, kpts,
                                           gamma, beta, bn, b2, w2b, hst, out);
}

// Round 7
// 160.140 us; speedup vs baseline: 1.1812x; 1.1812x over previous
//
#include <hip/hip_runtime.h>
#include <math.h>

#define N_PTS 50000
#define CCH   64
#define KP    15
#define NH    32
#define SIGMA 0.7f
#define BN_EPS 1e-5f
#define LEAKY 0.1f
#define QB    16
#define CWS   18           // cwT row stride in bf16 (16 q + 2 pad -> 2-way banks, free)
#define STATS_BLOCKS 1024

typedef short bf16x8 __attribute__((ext_vector_type(8)));
typedef float floatx4 __attribute__((ext_vector_type(4)));

__device__ __forceinline__ unsigned short f2b(float f) {
    union { float f; unsigned u; } v; v.f = f;
    return (unsigned short)((v.u + 0x7FFFu + ((v.u >> 16) & 1u)) >> 16);  // RNE
}
__device__ __forceinline__ float b2f(unsigned short b) {
    union { unsigned u; float f; } v; v.u = ((unsigned)b) << 16;
    return v.f;
}

// ---------- K1: blocks [0,STATS): h = sf@W1 -> hst (bf16) + BN sum/sumsq.
//             blocks [STATS, STATS+30): repack W2 into bf16 B-fragment order. ----------
__global__ __launch_bounds__(256) void k_prep(const float* __restrict__ sf,
                                              const float* __restrict__ W1,
                                              const float* __restrict__ W2,
                                              float* __restrict__ bn,
                                              unsigned short* __restrict__ hst,
                                              unsigned short* __restrict__ w2b) {
    int t = threadIdx.x;
    if (blockIdx.x >= STATS_BLOCKS) {
        // w2b[((tile*2+kstep)*64+lane)*8+j] = bf16(W2[k][n]),
        //   k = kstep*32 + (lane>>4)*8 + j, n = tile*16 + (lane&15)
        int g = (blockIdx.x - STATS_BLOCKS) * 256 + t;   // 7680 exactly
        int lane = g & 63, s = (g >> 6) & 1, tt = g >> 7;
        int col = lane & 15, quad = lane >> 4;
        int base = (s * 32 + quad * 8) * 960 + tt * 16 + col;
        ushort4 lo, hi;
        lo.x = f2b(W2[base + 0 * 960]); lo.y = f2b(W2[base + 1 * 960]);
        lo.z = f2b(W2[base + 2 * 960]); lo.w = f2b(W2[base + 3 * 960]);
        hi.x = f2b(W2[base + 4 * 960]); hi.y = f2b(W2[base + 5 * 960]);
        hi.z = f2b(W2[base + 6 * 960]); hi.w = f2b(W2[base + 7 * 960]);
        *(ushort4*)(w2b + g * 8)     = lo;
        *(ushort4*)(w2b + g * 8 + 4) = hi;
        return;
    }
    int c = t & 63, ml = t >> 6;
    float w1c[64];
    #pragma unroll
    for (int i = 0; i < 64; ++i) w1c[i] = W1[i * 64 + c];
    __shared__ float rows[4][64];
    float acc_s = 0.f, acc_q = 0.f;
    for (int m0 = blockIdx.x * 4; m0 < N_PTS; m0 += STATS_BLOCKS * 4) {
        __syncthreads();
        ((float*)rows)[t] = sf[m0 * 64 + t];
        __syncthreads();
        float h = 0.f;
        #pragma unroll
        for (int i4 = 0; i4 < 16; ++i4) {
            float4 r = *(const float4*)&rows[ml][i4 * 4];
            h += r.x * w1c[i4 * 4] + r.y * w1c[i4 * 4 + 1]
               + r.z * w1c[i4 * 4 + 2] + r.w * w1c[i4 * 4 + 3];
        }
        acc_s += h;
        acc_q += h * h;
        hst[(m0 + ml) * 64 + c] = f2b(h);      // 128B/wave coalesced
    }
    __shared__ float red[2][256];
    red[0][t] = acc_s; red[1][t] = acc_q;
    __syncthreads();
    if (t < 64) {
        float s = red[0][t] + red[0][64 + t] + red[0][128 + t] + red[0][192 + t];
        float q = red[1][t] + red[1][64 + t] + red[1][128 + t] + red[1][192 + t];
        atomicAdd(&bn[t], s);
        atomicAdd(&bn[64 + t], q);
    }
}

// ---------- K2: fused main. 256 threads / 4 waves — the proven round-3 shape.
// (512/1024-thread variants made the compiler trim the unified VGPR budget to
// 64 -> 32 arch VGPRs -> no memory-level parallelism; R4/R5 regressions.)
__global__ __launch_bounds__(256, 4) void k_main(
    const float* __restrict__ q_pts, const float* __restrict__ s_pts,
    const float* __restrict__ s_feats, const int* __restrict__ nb,
    const float* __restrict__ kpts, const float* __restrict__ gamma,
    const float* __restrict__ beta, const float* __restrict__ bn,
    const float* __restrict__ b2, const unsigned short* __restrict__ w2b,
    const unsigned short* __restrict__ hst, float* __restrict__ out) {

    __shared__ __align__(16) unsigned short cwT[960 * CWS];  // 34.56 KB: cw[n][q] bf16
    __shared__ float abS[128];                               // BN fold a[64], b[64]
    __shared__ int   nCnt[QB];
    __shared__ int   nPack[QB][NH];                          // idx | (k<<20)
    __shared__ float nInf[QB][NH];

    int t = threadIdx.x;
    int lane = t & 63, wv = t >> 6;
    int m0 = blockIdx.x * QB;

    if (t < 64) {   // inline BN finalize
        float mu  = bn[t] * (1.0f / N_PTS);
        float var = bn[64 + t] * (1.0f / N_PTS) - mu * mu;
        float a   = gamma[t] * rsqrtf(var + BN_EPS);
        abS[t]      = a;
        abS[64 + t] = beta[t] - mu * a;
    } else if (t >= 64 && t < 64 + QB) {
        nCnt[t - 64] = 0;
    }
    ((int*)nPack)[t]         = 0;      // zero-pad for branch-free phase B
    ((int*)nPack)[t + 256]   = 0;
    ((float*)nInf)[t]        = 0.f;
    ((float*)nInf)[t + 256]  = 0.f;
    __syncthreads();

    // ---- A-fragments directly in registers: fold BN + leaky on bf16 h rows ----
    int row = lane & 15, half = lane >> 4;
    bf16x8 a0, a1;
    {
        const unsigned short* hrow = hst + (m0 + row) * 64 + half * 8;
        bf16x8 r0 = *(const bf16x8*)(hrow);        // c = half*8 + j
        bf16x8 r1 = *(const bf16x8*)(hrow + 32);   // c = 32 + half*8 + j
        #pragma unroll
        for (int j = 0; j < 8; ++j) {
            int c0 = half * 8 + j;
            float g0 = abS[c0] * b2f((unsigned short)r0[j]) + abS[64 + c0];
            g0 = g0 > 0.f ? g0 : LEAKY * g0;
            a0[j] = (short)f2b(g0);
            int c1 = 32 + c0;
            float g1 = abS[c1] * b2f((unsigned short)r1[j]) + abS[64 + c1];
            g1 = g1 > 0.f ? g1 : LEAKY * g1;
            a1[j] = (short)f2b(g1);
        }
    }

    // ---- phase A: cw = G @ W2 via MFMA; each wave owns 15 n-tiles ----
    {
        int col = lane & 15, quad = lane >> 4;
        for (int ti = 0; ti < 15; ++ti) {
            int tt = wv * 15 + ti;
            bf16x8 bf0 = *(const bf16x8*)(w2b + ((tt * 2 + 0) * 64 + lane) * 8);
            bf16x8 bf1 = *(const bf16x8*)(w2b + ((tt * 2 + 1) * 64 + lane) * 8);
            floatx4 acc = {0.f, 0.f, 0.f, 0.f};
            acc = __builtin_amdgcn_mfma_f32_16x16x32_bf16(a0, bf0, acc, 0, 0, 0);
            acc = __builtin_amdgcn_mfma_f32_16x16x32_bf16(a1, bf1, acc, 0, 0, 0);
            int n = tt * 16 + col;
            float bb = b2[n];
            unsigned short* dst = &cwT[n * CWS + quad * 4];   // D: row(q)=quad*4+reg
            ushort2 w01, w23;
            w01.x = f2b(acc[0] + bb); w01.y = f2b(acc[1] + bb);
            w23.x = f2b(acc[2] + bb); w23.y = f2b(acc[3] + bb);
            *(ushort2*)(dst)     = w01;
            *(ushort2*)(dst + 2) = w23;
        }
    }

    // ---- hoist kernel points (wave-uniform address -> scalar loads, regs) ----
    float kpr[45];
    #pragma unroll
    for (int i = 0; i < 45; ++i) kpr[i] = kpts[i];

    // ---- phase 1: neighbor 1-NN kernel point + influence, compacted ----
    for (int task = t; task < QB * NH; task += 256) {
        int q = task >> 5, hh = task & 31;
        int m = m0 + q;
        int idx = nb[m * NH + hh];
        float px = s_pts[idx * 3 + 0] - q_pts[m * 3 + 0];
        float py = s_pts[idx * 3 + 1] - q_pts[m * 3 + 1];
        float pz = s_pts[idx * 3 + 2] - q_pts[m * 3 + 2];
        float best = 1e30f; int bi = 0;
        #pragma unroll
        for (int k = 0; k < KP; ++k) {
            float dx = px - kpr[k * 3], dy = py - kpr[k * 3 + 1], dz = pz - kpr[k * 3 + 2];
            float d = dx * dx + dy * dy + dz * dz;
            if (d < best) { best = d; bi = k; }
        }
        float infl = 1.f - sqrtf(best) * (1.0f / SIGMA);
        if (infl > 0.f) {
            int pos = atomicAdd(&nCnt[q], 1);
            nPack[q][pos] = idx | (bi << 20);
            nInf[q][pos]  = infl;
        }
    }
    __syncthreads();

    // ---- phase B: wave owns 4 queries, processed as 2 pairs; each pair
    //      interleaved 2-wide -> 4 gathers + 4 LDS reads in flight ----
    {
        int c = lane;
        #pragma unroll
        for (int pp = 0; pp < 2; ++pp) {
            int qa = wv * 4 + pp * 2, qb = qa + 1;
            int nA = nCnt[qa], nB = nCnt[qb];
            int na = nA > nB ? nA : nB;
            float accA = 0.f, accB = 0.f;
            for (int jj = 0; jj < na; jj += 2) {
                int2   pa = *(const int2*)&nPack[qa][jj];   // zero-padded: safe
                int2   pb = *(const int2*)&nPack[qb][jj];
                float2 ia = *(const float2*)&nInf[qa][jj];
                float2 ib = *(const float2*)&nInf[qb][jj];
                float fA0 = s_feats[(pa.x & 0xFFFFF) * 64 + c];
                float fA1 = s_feats[(pa.y & 0xFFFFF) * 64 + c];
                float fB0 = s_feats[(pb.x & 0xFFFFF) * 64 + c];
                float fB1 = s_feats[(pb.y & 0xFFFFF) * 64 + c];
                float wA0 = b2f(cwT[((pa.x >> 20) * 64 + c) * CWS + qa]);
                float wA1 = b2f(cwT[((pa.y >> 20) * 64 + c) * CWS + qa]);
                float wB0 = b2f(cwT[((pb.x >> 20) * 64 + c) * CWS + qb]);
                float wB1 = b2f(cwT[((pb.y >> 20) * 64 + c) * CWS + qb]);
                accA += ia.x * fA0 * wA0 + ia.y * fA1 * wA1;
                accB += ib.x * fB0 * wB0 + ib.y * fB1 * wB1;
            }
            out[(m0 + qa) * 64 + c] = accA;
            out[(m0 + qb) * 64 + c] = accB;
        }
    }
}

extern "C" void kernel_launch(void* const* d_in, const int* in_sizes, int n_in,
                              void* d_out, int out_size, void* d_ws, size_t ws_size,
                              hipStream_t stream) {
    const float* q_pts   = (const float*)d_in[0];
    const float* s_pts   = (const float*)d_in[1];
    const float* s_feats = (const float*)d_in[2];
    const int*   nb      = (const int*)d_in[3];
    const float* kpts    = (const float*)d_in[4];
    const float* W1      = (const float*)d_in[5];
    const float* gamma   = (const float*)d_in[6];
    const float* beta    = (const float*)d_in[7];
    const float* W2      = (const float*)d_in[8];
    const float* b2      = (const float*)d_in[9];
    float* out = (float*)d_out;

    float* ws = (float*)d_ws;
    float* bn = ws;                                        // 128 fp32
    unsigned short* w2b = (unsigned short*)(ws + 128);     // 61440 bf16 (122880 B)
    unsigned short* hst = w2b + 61440;                     // 50000*64 bf16 (6.4 MB)

    hipMemsetAsync(bn, 0, 128 * sizeof(float), stream);
    k_prep<<<STATS_BLOCKS + 30, 256, 0, stream>>>(s_feats, W1, W2, bn, hst, w2b);
    k_main<<<N_PTS / QB, 256, 0, stream>>>(q_pts, s_pts, s_feats, nb, kpts,
                                           gamma, beta, bn, b2, w2b, hst, out);
}

// Round 8
// 158.344 us; speedup vs baseline: 1.1946x; 1.0113x over previous
//
#include <hip/hip_runtime.h>
#include <math.h>

#define N_PTS 50000
#define CCH   64
#define KP    15
#define NH    32
#define SIGMA 0.7f
#define BN_EPS 1e-5f
#define LEAKY 0.1f
#define QB    16
#define CWS   18           // cwT row stride in bf16 (16 q + 2 pad -> 2-way banks, free)
#define STATS_BLOCKS 1024

typedef short bf16x8 __attribute__((ext_vector_type(8)));
typedef float floatx4 __attribute__((ext_vector_type(4)));

__device__ __forceinline__ unsigned short f2b(float f) {
    union { float f; unsigned u; } v; v.f = f;
    return (unsigned short)((v.u + 0x7FFFu + ((v.u >> 16) & 1u)) >> 16);  // RNE
}
__device__ __forceinline__ float b2f(unsigned short b) {
    union { unsigned u; float f; } v; v.u = ((unsigned)b) << 16;
    return v.f;
}

// ---------- K1: blocks [0,STATS): h = sf@W1 -> hst (bf16) + BN sum/sumsq
//             + bf16 shadow copy of s_feats (sfb).
//             blocks [STATS, STATS+30): repack W2 into bf16 B-fragment order. ----------
__global__ __launch_bounds__(256) void k_prep(const float* __restrict__ sf,
                                              const float* __restrict__ W1,
                                              const float* __restrict__ W2,
                                              float* __restrict__ bn,
                                              unsigned short* __restrict__ hst,
                                              unsigned short* __restrict__ w2b,
                                              unsigned short* __restrict__ sfb) {
    int t = threadIdx.x;
    if (blockIdx.x >= STATS_BLOCKS) {
        // w2b[((tile*2+kstep)*64+lane)*8+j] = bf16(W2[k][n]),
        //   k = kstep*32 + (lane>>4)*8 + j, n = tile*16 + (lane&15)
        int g = (blockIdx.x - STATS_BLOCKS) * 256 + t;   // 7680 exactly
        int lane = g & 63, s = (g >> 6) & 1, tt = g >> 7;
        int col = lane & 15, quad = lane >> 4;
        int base = (s * 32 + quad * 8) * 960 + tt * 16 + col;
        ushort4 lo, hi;
        lo.x = f2b(W2[base + 0 * 960]); lo.y = f2b(W2[base + 1 * 960]);
        lo.z = f2b(W2[base + 2 * 960]); lo.w = f2b(W2[base + 3 * 960]);
        hi.x = f2b(W2[base + 4 * 960]); hi.y = f2b(W2[base + 5 * 960]);
        hi.z = f2b(W2[base + 6 * 960]); hi.w = f2b(W2[base + 7 * 960]);
        *(ushort4*)(w2b + g * 8)     = lo;
        *(ushort4*)(w2b + g * 8 + 4) = hi;
        return;
    }
    int c = t & 63, ml = t >> 6;
    float w1c[64];
    #pragma unroll
    for (int i = 0; i < 64; ++i) w1c[i] = W1[i * 64 + c];
    __shared__ float rows[4][64];
    float acc_s = 0.f, acc_q = 0.f;
    for (int m0 = blockIdx.x * 4; m0 < N_PTS; m0 += STATS_BLOCKS * 4) {
        __syncthreads();
        float v = sf[m0 * 64 + t];
        ((float*)rows)[t] = v;
        sfb[m0 * 64 + t] = f2b(v);             // bf16 shadow for phase-B gathers
        __syncthreads();
        float h = 0.f;
        #pragma unroll
        for (int i4 = 0; i4 < 16; ++i4) {
            float4 r = *(const float4*)&rows[ml][i4 * 4];
            h += r.x * w1c[i4 * 4] + r.y * w1c[i4 * 4 + 1]
               + r.z * w1c[i4 * 4 + 2] + r.w * w1c[i4 * 4 + 3];
        }
        acc_s += h;
        acc_q += h * h;
        hst[(m0 + ml) * 64 + c] = f2b(h);      // 128B/wave coalesced
    }
    __shared__ float red[2][256];
    red[0][t] = acc_s; red[1][t] = acc_q;
    __syncthreads();
    if (t < 64) {
        float s = red[0][t] + red[0][64 + t] + red[0][128 + t] + red[0][192 + t];
        float q = red[1][t] + red[1][64 + t] + red[1][128 + t] + red[1][192 + t];
        atomicAdd(&bn[t], s);
        atomicAdd(&bn[64 + t], q);
    }
}

// ---------- K2: fused main. 256 threads / 4 waves — the proven round-3 shape.
// (512/1024-thread variants made the compiler trim the unified VGPR budget to
// 64 -> 32 arch VGPRs -> no memory-level parallelism; R4/R5 regressions.)
__global__ __launch_bounds__(256, 4) void k_main(
    const float* __restrict__ q_pts, const float* __restrict__ s_pts,
    const unsigned short* __restrict__ sfb, const int* __restrict__ nb,
    const float* __restrict__ kpts, const float* __restrict__ gamma,
    const float* __restrict__ beta, const float* __restrict__ bn,
    const float* __restrict__ b2, const unsigned short* __restrict__ w2b,
    const unsigned short* __restrict__ hst, float* __restrict__ out) {

    __shared__ __align__(16) unsigned short cwT[960 * CWS];  // 34.56 KB: cw[n][q] bf16
    __shared__ float abS[128];                               // BN fold a[64], b[64]
    __shared__ int      nCnt[QB];
    __shared__ unsigned nPack[QB][NH];        // idx(0:15) | (k*1152)(16:30)
    __shared__ float    nInf[QB][NH];

    int t = threadIdx.x;
    int lane = t & 63, wv = t >> 6;
    int m0 = blockIdx.x * QB;

    if (t < 64) {   // inline BN finalize
        float mu  = bn[t] * (1.0f / N_PTS);
        float var = bn[64 + t] * (1.0f / N_PTS) - mu * mu;
        float a   = gamma[t] * rsqrtf(var + BN_EPS);
        abS[t]      = a;
        abS[64 + t] = beta[t] - mu * a;
    } else if (t >= 64 && t < 64 + QB) {
        nCnt[t - 64] = 0;
    }
    ((unsigned*)nPack)[t]    = 0u;    // zero-pad for branch-free phase B
    ((unsigned*)nPack)[t + 256] = 0u;
    ((float*)nInf)[t]        = 0.f;
    ((float*)nInf)[t + 256]  = 0.f;
    __syncthreads();

    // ---- A-fragments directly in registers: fold BN + leaky on bf16 h rows ----
    int row = lane & 15, half = lane >> 4;
    bf16x8 a0, a1;
    {
        const unsigned short* hrow = hst + (m0 + row) * 64 + half * 8;
        bf16x8 r0 = *(const bf16x8*)(hrow);        // c = half*8 + j
        bf16x8 r1 = *(const bf16x8*)(hrow + 32);   // c = 32 + half*8 + j
        #pragma unroll
        for (int j = 0; j < 8; ++j) {
            int c0 = half * 8 + j;
            float g0 = abS[c0] * b2f((unsigned short)r0[j]) + abS[64 + c0];
            g0 = g0 > 0.f ? g0 : LEAKY * g0;
            a0[j] = (short)f2b(g0);
            int c1 = 32 + c0;
            float g1 = abS[c1] * b2f((unsigned short)r1[j]) + abS[64 + c1];
            g1 = g1 > 0.f ? g1 : LEAKY * g1;
            a1[j] = (short)f2b(g1);
        }
    }

    // ---- phase A: cw = G @ W2 via MFMA; each wave owns 15 n-tiles ----
    {
        int col = lane & 15, quad = lane >> 4;
        for (int ti = 0; ti < 15; ++ti) {
            int tt = wv * 15 + ti;
            bf16x8 bf0 = *(const bf16x8*)(w2b + ((tt * 2 + 0) * 64 + lane) * 8);
            bf16x8 bf1 = *(const bf16x8*)(w2b + ((tt * 2 + 1) * 64 + lane) * 8);
            floatx4 acc = {0.f, 0.f, 0.f, 0.f};
            acc = __builtin_amdgcn_mfma_f32_16x16x32_bf16(a0, bf0, acc, 0, 0, 0);
            acc = __builtin_amdgcn_mfma_f32_16x16x32_bf16(a1, bf1, acc, 0, 0, 0);
            int n = tt * 16 + col;
            float bb = b2[n];
            unsigned short* dst = &cwT[n * CWS + quad * 4];   // D: row(q)=quad*4+reg
            ushort2 w01, w23;
            w01.x = f2b(acc[0] + bb); w01.y = f2b(acc[1] + bb);
            w23.x = f2b(acc[2] + bb); w23.y = f2b(acc[3] + bb);
            *(ushort2*)(dst)     = w01;
            *(ushort2*)(dst + 2) = w23;
        }
    }

    // ---- hoist kernel points (wave-uniform address -> scalar loads, regs) ----
    float kpr[45];
    #pragma unroll
    for (int i = 0; i < 45; ++i) kpr[i] = kpts[i];

    // ---- phase 1: neighbor 1-NN kernel point + influence, compacted ----
    for (int task = t; task < QB * NH; task += 256) {
        int q = task >> 5, hh = task & 31;
        int m = m0 + q;
        int idx = nb[m * NH + hh];
        float px = s_pts[idx * 3 + 0] - q_pts[m * 3 + 0];
        float py = s_pts[idx * 3 + 1] - q_pts[m * 3 + 1];
        float pz = s_pts[idx * 3 + 2] - q_pts[m * 3 + 2];
        float best = 1e30f; int bi = 0;
        #pragma unroll
        for (int k = 0; k < KP; ++k) {
            float dx = px - kpr[k * 3], dy = py - kpr[k * 3 + 1], dz = pz - kpr[k * 3 + 2];
            float d = dx * dx + dy * dy + dz * dz;
            if (d < best) { best = d; bi = k; }
        }
        float infl = 1.f - sqrtf(best) * (1.0f / SIGMA);
        if (infl > 0.f) {
            int pos = atomicAdd(&nCnt[q], 1);
            // pre-scaled LDS offset: k*64*CWS ushorts (max 14*1152=16128, 15 bits)
            nPack[q][pos] = (unsigned)idx | ((unsigned)(bi * (64 * CWS)) << 16);
            nInf[q][pos]  = infl;
        }
    }
    __syncthreads();

    // ---- phase B: wave owns 4 queries, processed as 2 pairs; each pair
    //      interleaved 2-wide -> 4 bf16 gathers + 4 LDS reads in flight ----
    {
        int c = lane;
        #pragma unroll
        for (int pp = 0; pp < 2; ++pp) {
            int qa = wv * 4 + pp * 2, qb = qa + 1;
            const unsigned short* cwa = cwT + c * CWS + qa;   // per-lane cw base
            const unsigned short* cwb = cwa + 1;
            int nA = nCnt[qa], nB = nCnt[qb];
            int na = nA > nB ? nA : nB;
            float accA = 0.f, accB = 0.f;
            for (int jj = 0; jj < na; jj += 2) {
                uint2  pa = *(const uint2*)&nPack[qa][jj];   // zero-padded: safe
                uint2  pb = *(const uint2*)&nPack[qb][jj];
                float2 ia = *(const float2*)&nInf[qa][jj];
                float2 ib = *(const float2*)&nInf[qb][jj];
                float fA0 = b2f(sfb[(pa.x & 0xFFFFu) * 64 + c]);
                float fA1 = b2f(sfb[(pa.y & 0xFFFFu) * 64 + c]);
                float fB0 = b2f(sfb[(pb.x & 0xFFFFu) * 64 + c]);
                float fB1 = b2f(sfb[(pb.y & 0xFFFFu) * 64 + c]);
                float wA0 = b2f(cwa[pa.x >> 16]);
                float wA1 = b2f(cwa[pa.y >> 16]);
                float wB0 = b2f(cwb[pb.x >> 16]);
                float wB1 = b2f(cwb[pb.y >> 16]);
                accA += ia.x * fA0 * wA0 + ia.y * fA1 * wA1;
                accB += ib.x * fB0 * wB0 + ib.y * fB1 * wB1;
            }
            out[(m0 + qa) * 64 + c] = accA;
            out[(m0 + qb) * 64 + c] = accB;
        }
    }
}

extern "C" void kernel_launch(void* const* d_in, const int* in_sizes, int n_in,
                              void* d_out, int out_size, void* d_ws, size_t ws_size,
                              hipStream_t stream) {
    const float* q_pts   = (const float*)d_in[0];
    const float* s_pts   = (const float*)d_in[1];
    const float* s_feats = (const float*)d_in[2];
    const int*   nb      = (const int*)d_in[3];
    const float* kpts    = (const float*)d_in[4];
    const float* W1      = (const float*)d_in[5];
    const float* gamma   = (const float*)d_in[6];
    const float* beta    = (const float*)d_in[7];
    const float* W2      = (const float*)d_in[8];
    const float* b2      = (const float*)d_in[9];
    float* out = (float*)d_out;

    float* ws = (float*)d_ws;
    float* bn = ws;                                        // 128 fp32
    unsigned short* w2b = (unsigned short*)(ws + 128);     // 61440 bf16 (122880 B)
    unsigned short* hst = w2b + 61440;                     // 50000*64 bf16 (6.4 MB)
    unsigned short* sfb = hst + N_PTS * CCH;               // 50000*64 bf16 (6.4 MB)

    hipMemsetAsync(bn, 0, 128 * sizeof(float), stream);
    k_prep<<<STATS_BLOCKS + 30, 256, 0, stream>>>(s_feats, W1, W2, bn, hst, w2b, sfb);
    k_main<<<N_PTS / QB, 256, 0, stream>>>(q_pts, s_pts, sfb, nb, kpts,
                                           gamma, beta, bn, b2, w2b, hst, out);
}